// Round 6
// baseline (199.428 us; speedup 1.0000x reference)
//
#include <hip/hip_runtime.h>

#define T_DIM 2048
#define B_DIM 16
#define C_DIM 512
#define NW 56                         // H*K

// ---- conv3 LDS map: xs (bf16 14x512, swizzled) + wt (fp32 8x56)
#define XS3_BYTES (14 * 512 * 2)      // 14336 B
#define C3_WT_OFF XS3_BYTES
#define C3_LDS    (XS3_BYTES + 8 * NW * 4)   // 16128 B -> 8 blocks/CU (32 waves)

typedef __attribute__((ext_vector_type(8))) short short8;
typedef __attribute__((ext_vector_type(4))) float floatx4;

static __device__ __forceinline__ unsigned short f2bf(float x_) {
    union { float f; unsigned u; } v; v.f = x_;
    return (unsigned short)((v.u + 0x7FFFu + ((v.u >> 16) & 1u)) >> 16);  // RNE
}
static __device__ __forceinline__ float bf_lo(unsigned u) {
    union { unsigned u; float f; } c; c.u = u << 16; return c.f;
}
static __device__ __forceinline__ float bf_hi(unsigned u) {
    union { unsigned u; float f; } c; c.u = u & 0xFFFF0000u; return c.f;
}
// 16B-block XOR swizzle for the bf16 xs layout: bank-group bits [6:4] ^= addr[9:7].
// Conv read pattern (lane stride 112 B) lands all 64 lanes on distinct groups.
static __device__ __forceinline__ int swz(int a) { return a ^ ((a >> 3) & 0x70); }

// ---------------------------------------------------------------------------
// Pre-kernel: pack W (512x56 fp32) into bf16 MFMA B-fragments, HEAD-PACKED:
// n-tile nt covers global cols n = nt*14 + c, c in 0..13 (heads 2nt, 2nt+1);
// c = 14,15 zero-pad; softmax groups of 7 stay inside one wave's 16-col tile.
// Bg[(ks*4+nt)*64 + l][j] = W[k = ks*32+((l>>4)&3)*8+j][n], l&15 = c.
// ---------------------------------------------------------------------------
__global__ __launch_bounds__(256)
void pack_w(const float* __restrict__ W, short8* __restrict__ Bg) {
    const int g  = blockIdx.x * 256 + threadIdx.x;   // 0..4095
    const int ks = g >> 8;
    const int nt = (g >> 6) & 3;
    const int l  = g & 63;
    const int c  = l & 15;
    const int n  = nt * 14 + c;
    const int k0 = ks * 32 + ((l >> 4) & 3) * 8;
    short8 o;
#pragma unroll
    for (int j = 0; j < 8; ++j) {
        const float v = (c < 14) ? W[(size_t)(k0 + j) * NW + n] : 0.f;
        o[j] = (short)f2bf(v);
    }
    Bg[g] = o;
}

// ---------------------------------------------------------------------------
// Kernel W: logits GEMM + in-wave softmax -> wt_g (fp32, global).
// Block = 16 t x 1 b, 4 waves; wave wv owns n-tile wv (heads 2wv, 2wv+1).
// ONE barrier (A8 staging). Unchanged from R5 (validated).
// ---------------------------------------------------------------------------
__global__ __launch_bounds__(256)
void weight2(const float* __restrict__ q, const short8* __restrict__ Bg,
             float* __restrict__ wt_g) {
    __shared__ __align__(16) short8 A8[16 * 64];   // 16384 B

    const int tid  = threadIdx.x;
    const int lane = tid & 63;
    const int wv   = tid >> 6;                 // wave id = n-tile
    const int b    = blockIdx.x & 15;
    const int t0   = (blockIdx.x >> 4) * 16;

    const int rq = lane & 15;                  // A row (= t within tile)
    const int qq = lane >> 4;                  // quad -> k sub-offset
    const float* qrow = q + ((size_t)(t0 + rq) * B_DIM + b) * C_DIM + qq * 8;
#pragma unroll
    for (int s = 0; s < 4; ++s) {
        const int ks = wv + s * 4;
        const float4 f0 = *(const float4*)(qrow + ks * 32);
        const float4 f1 = *(const float4*)(qrow + ks * 32 + 4);
        short8 o;
        o[0] = (short)f2bf(f0.x); o[1] = (short)f2bf(f0.y);
        o[2] = (short)f2bf(f0.z); o[3] = (short)f2bf(f0.w);
        o[4] = (short)f2bf(f1.x); o[5] = (short)f2bf(f1.y);
        o[6] = (short)f2bf(f1.z); o[7] = (short)f2bf(f1.w);
        A8[ks * 64 + lane] = o;
    }
    __syncthreads();

    floatx4 acc = (floatx4){0.f, 0.f, 0.f, 0.f};
#pragma unroll
    for (int ks = 0; ks < 16; ++ks) {
        const short8 bf = Bg[(ks * 4 + wv) * 64 + lane];
        acc = __builtin_amdgcn_mfma_f32_16x16x32_bf16(A8[ks * 64 + lane], bf,
                                                      acc, 0, 0, 0);
    }

    const int c    = lane & 15;
    const int cb   = (c < 7) ? 0 : 7;
    const int sb   = (lane & 48) + cb;
    const int quad = lane >> 4;
#pragma unroll
    for (int r = 0; r < 4; ++r) {
        const float a = acc[r];
        const float v0 = __shfl(a, sb + 0);
        const float v1 = __shfl(a, sb + 1);
        const float v2 = __shfl(a, sb + 2);
        const float v3 = __shfl(a, sb + 3);
        const float v4 = __shfl(a, sb + 4);
        const float v5 = __shfl(a, sb + 5);
        const float v6 = __shfl(a, sb + 6);
        const float mx = fmaxf(fmaxf(fmaxf(v0, v1), fmaxf(v2, v3)),
                               fmaxf(fmaxf(v4, v5), v6));
        const float sm = __expf(v0 - mx) + __expf(v1 - mx) + __expf(v2 - mx) +
                         __expf(v3 - mx) + __expf(v4 - mx) + __expf(v5 - mx) +
                         __expf(v6 - mx);
        const float w = __expf(a - mx) * (1.0f / sm);
        if (c < 14)
            wt_g[((size_t)(t0 + quad * 4 + r) * B_DIM + b) * NW + wv * 14 + c] = w;
    }
}

// ---------------------------------------------------------------------------
// Kernel C: conv, 8-row tiles. Block = 8 t x 1 b, 256 threads (4 waves),
// ONE barrier, LDS 16128 B -> 8 blocks/CU resident (32 waves, 100% cap).
// XCD-bijective swizzle co-locates one t-chunk's 16 b-blocks per XCD L2.
// Wave wv owns rows tt = wv*2 + s, s in {0,1}.
// ---------------------------------------------------------------------------
__global__ __launch_bounds__(256, 8)
void conv3(const float* __restrict__ x, const float* __restrict__ wt_g,
           float* __restrict__ out) {
    __shared__ __align__(16) char S[C3_LDS];

    const int tid  = threadIdx.x;
    const int lane = tid & 63;
    const int wv   = tid >> 6;                 // 0..3
    // bijective XCD swizzle: grid 4096, 8 XCDs -> XCD k serves logical
    // blocks [k*512, (k+1)*512): contiguous t-chunks x all b (L2 locality).
    const int bid = blockIdx.x;
    const int lg  = (bid & 7) * 512 + (bid >> 3);
    const int b   = lg & 15;
    const int t0  = (lg >> 4) * 8;

    // issue x-window loads (14 padded rows x 512 fp32 = 1792 float4 = 7/thread)
    float4 xr[7];
#pragma unroll
    for (int j = 0; j < 7; ++j) {
        const int idx = tid + j * 256;
        const int i   = idx >> 7;              // padded row 0..13
        const int cc  = (idx & 127) * 4;
        const int tp  = t0 + i - 3;
        xr[j] = make_float4(0.f, 0.f, 0.f, 0.f);
        if (tp >= 0 && tp < T_DIM)
            xr[j] = *(const float4*)(x + ((size_t)tp * B_DIM + b) * C_DIM + cc);
    }
    // issue wt load (8 rows x 14 float4 = 112 float4)
    float4 wld = make_float4(0.f, 0.f, 0.f, 0.f);
    const int wrow = tid / 14;
    const int wj   = tid - wrow * 14;
    if (tid < 112)
        wld = *(const float4*)(wt_g + ((size_t)(t0 + wrow) * B_DIM + b) * NW + wj * 4);

    // convert x -> bf16 xs (swizzled), stage wt
    char* XS = S;
#pragma unroll
    for (int j = 0; j < 7; ++j) {
        const int idx = tid + j * 256;
        uint2 p;
        p.x = (unsigned)f2bf(xr[j].x) | ((unsigned)f2bf(xr[j].y) << 16);
        p.y = (unsigned)f2bf(xr[j].z) | ((unsigned)f2bf(xr[j].w) << 16);
        *(uint2*)(XS + swz(idx * 8)) = p;
    }
    if (tid < 112)
        *(float4*)(S + C3_WT_OFF + (wrow * NW + wj * 4) * 4) = wld;
    __syncthreads();

    // conv: lane owns outputs 8l..8l+8 = window bytes [112l, 112l+112)
    const float* wt = (const float*)(S + C3_WT_OFF);
    const int h = lane >> 3;
    const int base_b = lane * 112;
#pragma unroll
    for (int s = 0; s < 2; ++s) {
        const int tt = wv * 2 + s;
        const int tb = tt * 1024 + base_b;
        uint4 xu[7];
#pragma unroll
        for (int i = 0; i < 7; ++i)
            xu[i] = *(const uint4*)(XS + swz(tb + i * 16));
        float xf[56];
#pragma unroll
        for (int i = 0; i < 7; ++i) {
            xf[i * 8 + 0] = bf_lo(xu[i].x); xf[i * 8 + 1] = bf_hi(xu[i].x);
            xf[i * 8 + 2] = bf_lo(xu[i].y); xf[i * 8 + 3] = bf_hi(xu[i].y);
            xf[i * 8 + 4] = bf_lo(xu[i].z); xf[i * 8 + 5] = bf_hi(xu[i].z);
            xf[i * 8 + 6] = bf_lo(xu[i].w); xf[i * 8 + 7] = bf_hi(xu[i].w);
        }
        const float* wp = wt + tt * NW + h * 7;
        float w[7];
#pragma unroll
        for (int k = 0; k < 7; ++k) w[k] = wp[k];
        float a8[8];
#pragma unroll
        for (int r = 0; r < 8; ++r) {
            float sacc = xf[r * 7] * w[0];
#pragma unroll
            for (int k = 1; k < 7; ++k) sacc = fmaf(w[k], xf[r * 7 + k], sacc);
            a8[r] = sacc;
        }
        float* orow = out + ((size_t)(t0 + tt) * B_DIM + b) * C_DIM + lane * 8;
        const floatx4 v0 = (floatx4){a8[0], a8[1], a8[2], a8[3]};
        const floatx4 v1 = (floatx4){a8[4], a8[5], a8[6], a8[7]};
        __builtin_nontemporal_store(v0, (floatx4*)orow);
        __builtin_nontemporal_store(v1, (floatx4*)(orow + 4));
    }
}

extern "C" void kernel_launch(void* const* d_in, const int* in_sizes, int n_in,
                              void* d_out, int out_size, void* d_ws, size_t ws_size,
                              hipStream_t stream) {
    const float* x = (const float*)d_in[0];
    const float* q = (const float*)d_in[1];
    const float* W = (const float*)d_in[2];
    float* out = (float*)d_out;
    short8* Bg  = (short8*)d_ws;                       // 64 KB packed B-fragments
    float* wt_g = (float*)((char*)d_ws + 65536);       // 7.34 MB weights

    pack_w<<<16, 256, 0, stream>>>(W, Bg);
    weight2<<<(T_DIM / 16) * B_DIM, 256, 0, stream>>>(q, Bg, wt_g);
    conv3<<<(T_DIM / 8) * B_DIM, 256, 0, stream>>>(x, wt_g, out);
}

// Round 7
// 175.989 us; speedup vs baseline: 1.1332x; 1.1332x over previous
//
#include <hip/hip_runtime.h>

#define T_DIM 2048
#define B_DIM 16
#define C_DIM 512
#define NW 56                         // H*K

// ---- LDS map: A8 frags (16 KB) + xs (bf16 22x512, swizzled) + wt (fp32 16x56)
#define A_BYTES  16384
#define XS_OFF   A_BYTES
#define XS_BYTES (22 * 512 * 2)       // 22528 B
#define WT_OFF   (A_BYTES + XS_BYTES) // 38912
#define F_LDS    (WT_OFF + 16 * NW * 4)   // 42496 B -> 3 blocks/CU (24 waves)

typedef __attribute__((ext_vector_type(8))) short short8;
typedef __attribute__((ext_vector_type(4))) float floatx4;

static __device__ __forceinline__ unsigned short f2bf(float x_) {
    union { float f; unsigned u; } v; v.f = x_;
    return (unsigned short)((v.u + 0x7FFFu + ((v.u >> 16) & 1u)) >> 16);  // RNE
}
static __device__ __forceinline__ float bf_lo(unsigned u) {
    union { unsigned u; float f; } c; c.u = u << 16; return c.f;
}
static __device__ __forceinline__ float bf_hi(unsigned u) {
    union { unsigned u; float f; } c; c.u = u & 0xFFFF0000u; return c.f;
}
// xs swizzle: bank-group bits [6:4] ^= addr[9:7] (validated, conv reads clean)
static __device__ __forceinline__ int swz(int a) { return a ^ ((a >> 3) & 0x70); }
// A8 swizzle: bits [6:4] ^= (bits[10:8] ^ bits[13:11]); involution; makes the
// fragment-order staging writes ~2-way and keeps frag reads (lane*16) unique.
static __device__ __forceinline__ int aswz(int a) {
    return a ^ ((((a >> 8) ^ (a >> 11)) & 7) << 4);
}

// ---------------------------------------------------------------------------
// Pre-kernel: pack W (512x56 fp32) into bf16 MFMA B-fragments, HEAD-PACKED:
// n-tile nt covers cols n = nt*14 + c, c in 0..13 (heads 2nt,2nt+1); c=14,15
// zero-pad, so each softmax group of 7 lives inside one wave's 16-col tile.
// Bg[(ks*4+nt)*64 + l][j] = W[k = ks*32+((l>>4)&3)*8+j][n], l&15 = c.
// ---------------------------------------------------------------------------
__global__ __launch_bounds__(256)
void pack_w(const float* __restrict__ W, short8* __restrict__ Bg) {
    const int g  = blockIdx.x * 256 + threadIdx.x;   // 0..4095
    const int ks = g >> 8;
    const int nt = (g >> 6) & 3;
    const int l  = g & 63;
    const int c  = l & 15;
    const int n  = nt * 14 + c;
    const int k0 = ks * 32 + ((l >> 4) & 3) * 8;
    short8 o;
#pragma unroll
    for (int j = 0; j < 8; ++j) {
        const float v = (c < 14) ? W[(size_t)(k0 + j) * NW + n] : 0.f;
        o[j] = (short)f2bf(v);
    }
    Bg[g] = o;
}

// ---------------------------------------------------------------------------
// Fused kernel: block = 16 t x 1 b, 512 threads (8 waves), TWO barriers.
//  1. coalesced q-tile + x-window loads (4 + 6 float4/thread)
//  2. stage q straight into MFMA fragment order (aswz), x -> bf16 xs (swz)
//  3. barrier; waves 0-3: 16-MFMA chain (B frags from L2-hot global) +
//     in-wave softmax -> wt LDS; waves 4-7 pass through
//  4. barrier; all 8 waves: conv (2 rows each), plain float4 stores
// ---------------------------------------------------------------------------
__global__ __launch_bounds__(512, 6)
void fused3(const float* __restrict__ x, const float* __restrict__ q,
            const short8* __restrict__ Bg, float* __restrict__ out) {
    __shared__ __align__(16) char S[F_LDS];

    const int tid  = threadIdx.x;
    const int lane = tid & 63;
    const int wv   = tid >> 6;                 // 0..7
    const int b    = blockIdx.x & 15;
    const int t0   = (blockIdx.x >> 4) * 16;

    // ---- issue q-tile loads (16 rows x 512 fp32 = 2048 float4, 4/thread)
    float4 qr[4];
#pragma unroll
    for (int j = 0; j < 4; ++j) {
        const int idx = tid + j * 512;         // 0..2047
        const int r   = idx >> 7;              // row 0..15
        const int cc  = (idx & 127) * 4;
        qr[j] = *(const float4*)(q + ((size_t)(t0 + r) * B_DIM + b) * C_DIM + cc);
    }
    // ---- issue x-window loads (22 padded rows x 512 fp32 = 2816 float4)
    float4 xr[6];
#pragma unroll
    for (int j = 0; j < 6; ++j) {
        const int idx = tid + j * 512;
        xr[j] = make_float4(0.f, 0.f, 0.f, 0.f);
        if (idx < 2816) {
            const int i  = idx >> 7;           // padded row 0..21
            const int cc = (idx & 127) * 4;
            const int tp = t0 + i - 3;
            if (tp >= 0 && tp < T_DIM)
                xr[j] = *(const float4*)(x + ((size_t)tp * B_DIM + b) * C_DIM + cc);
        }
    }

    // ---- stage q into A8 fragment order: element (r,c) -> byte
    //      ks*1024 + qq*256 + r*16 + (c&7)*2, ks=c>>5, qq=(c>>3)&3 (aswz'd)
    char* AS = S;
#pragma unroll
    for (int j = 0; j < 4; ++j) {
        const int idx = tid + j * 512;
        const int r   = idx >> 7;
        const int cc  = (idx & 127) * 4;
        const int a   = (cc >> 5) * 1024 + ((cc >> 3) & 3) * 256 + r * 16 +
                        (cc & 7) * 2;
        uint2 p;
        p.x = (unsigned)f2bf(qr[j].x) | ((unsigned)f2bf(qr[j].y) << 16);
        p.y = (unsigned)f2bf(qr[j].z) | ((unsigned)f2bf(qr[j].w) << 16);
        *(uint2*)(AS + aswz(a)) = p;
    }
    // ---- stage x -> bf16 xs (swizzled)
    char* XS = S + XS_OFF;
#pragma unroll
    for (int j = 0; j < 6; ++j) {
        const int idx = tid + j * 512;
        if (idx < 2816) {
            uint2 p;
            p.x = (unsigned)f2bf(xr[j].x) | ((unsigned)f2bf(xr[j].y) << 16);
            p.y = (unsigned)f2bf(xr[j].z) | ((unsigned)f2bf(xr[j].w) << 16);
            *(uint2*)(XS + swz(idx * 8)) = p;
        }
    }
    __syncthreads();

    // ---- MFMA + in-wave softmax: waves 0-3, n-tile = wv
    float* wt = (float*)(S + WT_OFF);
    if (wv < 4) {
        floatx4 acc = (floatx4){0.f, 0.f, 0.f, 0.f};
#pragma unroll
        for (int ks = 0; ks < 16; ++ks) {
            const short8 af = *(const short8*)(AS + aswz(ks * 1024 + lane * 16));
            const short8 bf = Bg[(ks * 4 + wv) * 64 + lane];
            acc = __builtin_amdgcn_mfma_f32_16x16x32_bf16(af, bf, acc, 0, 0, 0);
        }
        const int c    = lane & 15;
        const int cb   = (c < 7) ? 0 : 7;
        const int sb   = (lane & 48) + cb;
        const int quad = lane >> 4;
#pragma unroll
        for (int r = 0; r < 4; ++r) {
            const float a = acc[r];
            const float v0 = __shfl(a, sb + 0);
            const float v1 = __shfl(a, sb + 1);
            const float v2 = __shfl(a, sb + 2);
            const float v3 = __shfl(a, sb + 3);
            const float v4 = __shfl(a, sb + 4);
            const float v5 = __shfl(a, sb + 5);
            const float v6 = __shfl(a, sb + 6);
            const float mx = fmaxf(fmaxf(fmaxf(v0, v1), fmaxf(v2, v3)),
                                   fmaxf(fmaxf(v4, v5), v6));
            const float sm = __expf(v0 - mx) + __expf(v1 - mx) + __expf(v2 - mx) +
                             __expf(v3 - mx) + __expf(v4 - mx) + __expf(v5 - mx) +
                             __expf(v6 - mx);
            const float w = __expf(a - mx) * (1.0f / sm);
            if (c < 14)
                wt[(quad * 4 + r) * NW + wv * 14 + c] = w;
        }
    }
    __syncthreads();

    // ---- conv: lane owns outputs 8l..8l+8 = window bytes [112l, 112l+112)
    const int h = lane >> 3;
    const int base_b = lane * 112;
#pragma unroll
    for (int s = 0; s < 2; ++s) {
        const int tt = wv * 2 + s;
        const int tb = tt * 1024 + base_b;
        uint4 xu[7];
#pragma unroll
        for (int i = 0; i < 7; ++i)
            xu[i] = *(const uint4*)(XS + swz(tb + i * 16));
        float xf[56];
#pragma unroll
        for (int i = 0; i < 7; ++i) {
            xf[i * 8 + 0] = bf_lo(xu[i].x); xf[i * 8 + 1] = bf_hi(xu[i].x);
            xf[i * 8 + 2] = bf_lo(xu[i].y); xf[i * 8 + 3] = bf_hi(xu[i].y);
            xf[i * 8 + 4] = bf_lo(xu[i].z); xf[i * 8 + 5] = bf_hi(xu[i].z);
            xf[i * 8 + 6] = bf_lo(xu[i].w); xf[i * 8 + 7] = bf_hi(xu[i].w);
        }
        const float* wp = wt + tt * NW + h * 7;
        float w[7];
#pragma unroll
        for (int k = 0; k < 7; ++k) w[k] = wp[k];
        float a8[8];
#pragma unroll
        for (int r = 0; r < 8; ++r) {
            float sacc = xf[r * 7] * w[0];
#pragma unroll
            for (int k = 1; k < 7; ++k) sacc = fmaf(w[k], xf[r * 7 + k], sacc);
            a8[r] = sacc;
        }
        float* orow = out + ((size_t)(t0 + tt) * B_DIM + b) * C_DIM + lane * 8;
        *(float4*)(orow)     = make_float4(a8[0], a8[1], a8[2], a8[3]);
        *(float4*)(orow + 4) = make_float4(a8[4], a8[5], a8[6], a8[7]);
    }
}

extern "C" void kernel_launch(void* const* d_in, const int* in_sizes, int n_in,
                              void* d_out, int out_size, void* d_ws, size_t ws_size,
                              hipStream_t stream) {
    const float* x = (const float*)d_in[0];
    const float* q = (const float*)d_in[1];
    const float* W = (const float*)d_in[2];
    float* out = (float*)d_out;
    short8* Bg = (short8*)d_ws;   // 64 KB packed bf16 B-fragments (head-packed)

    pack_w<<<16, 256, 0, stream>>>(W, Bg);
    fused3<<<(T_DIM / 16) * B_DIM, 512, 0, stream>>>(x, q, Bg, out);
}

// Round 8
// 175.507 us; speedup vs baseline: 1.1363x; 1.0027x over previous
//
#include <hip/hip_runtime.h>

#define T_DIM 2048
#define B_DIM 16
#define C_DIM 512
#define NW 56                         // H*K

// ---- LDS map: A8 frags (16 KB, later overlaid by wt fp32 16x56) + xs bf16
#define XS_OFF   16384
#define XS_BYTES (22 * 512 * 2)       // 22528 B
#define F_LDS    (XS_OFF + XS_BYTES)  // 38912 B -> 4 blocks/CU (32 waves, 100%)

typedef __attribute__((ext_vector_type(8))) short short8;
typedef __attribute__((ext_vector_type(4))) float floatx4;

static __device__ __forceinline__ unsigned short f2bf(float x_) {
    union { float f; unsigned u; } v; v.f = x_;
    return (unsigned short)((v.u + 0x7FFFu + ((v.u >> 16) & 1u)) >> 16);  // RNE
}
static __device__ __forceinline__ float bf_lo(unsigned u) {
    union { unsigned u; float f; } c; c.u = u << 16; return c.f;
}
static __device__ __forceinline__ float bf_hi(unsigned u) {
    union { unsigned u; float f; } c; c.u = u & 0xFFFF0000u; return c.f;
}
// xs swizzle: bank-group bits [6:4] ^= addr[9:7] (validated, conv reads clean)
static __device__ __forceinline__ int swz(int a) { return a ^ ((a >> 3) & 0x70); }
// A8 swizzle: bits [6:4] ^= (bits[10:8] ^ bits[13:11]); involution (validated R7)
static __device__ __forceinline__ int aswz(int a) {
    return a ^ ((((a >> 8) ^ (a >> 11)) & 7) << 4);
}

// ---------------------------------------------------------------------------
// Pre-kernel: pack W (512x56 fp32) into bf16 MFMA B-fragments, HEAD-PACKED:
// n-tile nt covers cols n = nt*14 + c, c in 0..13 (heads 2nt,2nt+1); c=14,15
// zero-pad, so each softmax group of 7 lives inside one wave's 16-col tile.
// Bg[(ks*4+nt)*64 + l][j] = W[k = ks*32+((l>>4)&3)*8+j][n], l&15 = c.
// ---------------------------------------------------------------------------
__global__ __launch_bounds__(256)
void pack_w(const float* __restrict__ W, short8* __restrict__ Bg) {
    const int g  = blockIdx.x * 256 + threadIdx.x;   // 0..4095
    const int ks = g >> 8;
    const int nt = (g >> 6) & 3;
    const int l  = g & 63;
    const int c  = l & 15;
    const int n  = nt * 14 + c;
    const int k0 = ks * 32 + ((l >> 4) & 3) * 8;
    short8 o;
#pragma unroll
    for (int j = 0; j < 8; ++j) {
        const float v = (c < 14) ? W[(size_t)(k0 + j) * NW + n] : 0.f;
        o[j] = (short)f2bf(v);
    }
    Bg[g] = o;
}

// ---------------------------------------------------------------------------
// Fused kernel: block = 16 t x 1 b, 512 threads (8 waves), wave-specialized.
//  phase 0: waves 0-3 load+stage q into A8 frag order; waves 4-7 issue x loads
//  bar1
//  phase 1: waves 0-3: 16-MFMA (2 chains) + in-wave softmax (regs);
//           waves 4-7: stage x -> bf16 xs (CONCURRENT with MFMA)
//  bar2 (A8 now dead everywhere)
//  phase 2: waves 0-3 write wt (fp32 16x56) OVERLAYING the A8 region
//  bar3
//  phase 3: all 8 waves conv (2 rows each), plain float4 stores
// ---------------------------------------------------------------------------
__global__ __launch_bounds__(512, 8)
void fused4(const float* __restrict__ x, const float* __restrict__ q,
            const short8* __restrict__ Bg, float* __restrict__ out) {
    __shared__ __align__(16) char S[F_LDS];

    const int tid  = threadIdx.x;
    const int lane = tid & 63;
    const int wv   = tid >> 6;                 // 0..7
    const int b    = blockIdx.x & 15;
    const int t0   = (blockIdx.x >> 4) * 16;

    char*  AS = S;                             // A8 frags (phase 0-1)
    char*  XS = S + XS_OFF;                    // xs bf16 window
    float* wt = (float*)S;                     // overlays A8 from phase 2 on

    float4 xr[11];                             // live only in waves 4-7
    const int xtid = tid - 256;                // staging index for waves 4-7

    // ---- phase 0
    if (wv < 4) {
        // load q tile (16 rows x 512 fp32 = 2048 float4, 8 per thread)
        float4 qr[8];
#pragma unroll
        for (int j = 0; j < 8; ++j) {
            const int idx = tid + j * 256;     // 0..2047
            const int r   = idx >> 7;          // row 0..15
            const int cc  = (idx & 127) * 4;
            qr[j] = *(const float4*)(q + ((size_t)(t0 + r) * B_DIM + b) * C_DIM + cc);
        }
        // stage into A8 fragment order: (r,c) -> ks*1024 + qq*256 + r*16 + (c&7)*2
#pragma unroll
        for (int j = 0; j < 8; ++j) {
            const int idx = tid + j * 256;
            const int r   = idx >> 7;
            const int cc  = (idx & 127) * 4;
            const int a   = (cc >> 5) * 1024 + ((cc >> 3) & 3) * 256 + r * 16 +
                            (cc & 7) * 2;
            uint2 p;
            p.x = (unsigned)f2bf(qr[j].x) | ((unsigned)f2bf(qr[j].y) << 16);
            p.y = (unsigned)f2bf(qr[j].z) | ((unsigned)f2bf(qr[j].w) << 16);
            *(uint2*)(AS + aswz(a)) = p;
        }
    } else {
        // issue x-window loads (22 padded rows x 512 fp32 = 2816 float4, 11/thr)
#pragma unroll
        for (int j = 0; j < 11; ++j) {
            const int idx = xtid + j * 256;    // 0..2815
            const int i   = idx >> 7;          // padded row 0..21
            const int cc  = (idx & 127) * 4;
            const int tp  = t0 + i - 3;
            xr[j] = make_float4(0.f, 0.f, 0.f, 0.f);
            if (tp >= 0 && tp < T_DIM)
                xr[j] = *(const float4*)(x + ((size_t)tp * B_DIM + b) * C_DIM + cc);
        }
    }
    __syncthreads();   // bar1: A8 staged

    // ---- phase 1: MFMA+softmax (waves 0-3)  ||  xs staging (waves 4-7)
    float wres[4];
    if (wv < 4) {
        floatx4 acc0 = (floatx4){0.f, 0.f, 0.f, 0.f};
        floatx4 acc1 = (floatx4){0.f, 0.f, 0.f, 0.f};
#pragma unroll
        for (int ks = 0; ks < 16; ks += 2) {
            const short8 af0 = *(const short8*)(AS + aswz(ks * 1024 + lane * 16));
            const short8 bf0 = Bg[(ks * 4 + wv) * 64 + lane];
            acc0 = __builtin_amdgcn_mfma_f32_16x16x32_bf16(af0, bf0, acc0, 0, 0, 0);
            const short8 af1 = *(const short8*)(AS + aswz((ks + 1) * 1024 + lane * 16));
            const short8 bf1 = Bg[((ks + 1) * 4 + wv) * 64 + lane];
            acc1 = __builtin_amdgcn_mfma_f32_16x16x32_bf16(af1, bf1, acc1, 0, 0, 0);
        }
        const floatx4 acc = acc0 + acc1;
        // in-wave softmax over head groups of 7 (head-packed cols), into regs
        const int c  = lane & 15;
        const int cb = (c < 7) ? 0 : 7;
        const int sb = (lane & 48) + cb;
#pragma unroll
        for (int r = 0; r < 4; ++r) {
            const float a = acc[r];
            const float v0 = __shfl(a, sb + 0);
            const float v1 = __shfl(a, sb + 1);
            const float v2 = __shfl(a, sb + 2);
            const float v3 = __shfl(a, sb + 3);
            const float v4 = __shfl(a, sb + 4);
            const float v5 = __shfl(a, sb + 5);
            const float v6 = __shfl(a, sb + 6);
            const float mx = fmaxf(fmaxf(fmaxf(v0, v1), fmaxf(v2, v3)),
                                   fmaxf(fmaxf(v4, v5), v6));
            const float sm = __expf(v0 - mx) + __expf(v1 - mx) + __expf(v2 - mx) +
                             __expf(v3 - mx) + __expf(v4 - mx) + __expf(v5 - mx) +
                             __expf(v6 - mx);
            wres[r] = __expf(a - mx) * (1.0f / sm);
        }
    } else {
        // stage x -> bf16 xs (swizzled); overlaps the MFMA phase
#pragma unroll
        for (int j = 0; j < 11; ++j) {
            const int idx = xtid + j * 256;
            uint2 p;
            p.x = (unsigned)f2bf(xr[j].x) | ((unsigned)f2bf(xr[j].y) << 16);
            p.y = (unsigned)f2bf(xr[j].z) | ((unsigned)f2bf(xr[j].w) << 16);
            *(uint2*)(XS + swz(idx * 8)) = p;
        }
    }
    __syncthreads();   // bar2: A8 reads complete everywhere -> region reusable

    // ---- phase 2: wt write (overlay on dead A8 region)
    if (wv < 4) {
        const int c    = lane & 15;
        const int quad = lane >> 4;
        if (c < 14) {
#pragma unroll
            for (int r = 0; r < 4; ++r)
                wt[(quad * 4 + r) * NW + wv * 14 + c] = wres[r];
        }
    }
    __syncthreads();   // bar3: wt + xs visible

    // ---- phase 3: conv — lane owns outputs 8l..8l+8 = window bytes [112l,112l+112)
    const int h = lane >> 3;
    const int base_b = lane * 112;
#pragma unroll
    for (int s = 0; s < 2; ++s) {
        const int tt = wv * 2 + s;
        const int tb = tt * 1024 + base_b;
        uint4 xu[7];
#pragma unroll
        for (int i = 0; i < 7; ++i)
            xu[i] = *(const uint4*)(XS + swz(tb + i * 16));
        float xf[56];
#pragma unroll
        for (int i = 0; i < 7; ++i) {
            xf[i * 8 + 0] = bf_lo(xu[i].x); xf[i * 8 + 1] = bf_hi(xu[i].x);
            xf[i * 8 + 2] = bf_lo(xu[i].y); xf[i * 8 + 3] = bf_hi(xu[i].y);
            xf[i * 8 + 4] = bf_lo(xu[i].z); xf[i * 8 + 5] = bf_hi(xu[i].z);
            xf[i * 8 + 6] = bf_lo(xu[i].w); xf[i * 8 + 7] = bf_hi(xu[i].w);
        }
        const float* wp = wt + tt * NW + h * 7;
        float w[7];
#pragma unroll
        for (int k = 0; k < 7; ++k) w[k] = wp[k];
        float a8[8];
#pragma unroll
        for (int r = 0; r < 8; ++r) {
            float sacc = xf[r * 7] * w[0];
#pragma unroll
            for (int k = 1; k < 7; ++k) sacc = fmaf(w[k], xf[r * 7 + k], sacc);
            a8[r] = sacc;
        }
        float* orow = out + ((size_t)(t0 + tt) * B_DIM + b) * C_DIM + lane * 8;
        *(float4*)(orow)     = make_float4(a8[0], a8[1], a8[2], a8[3]);
        *(float4*)(orow + 4) = make_float4(a8[4], a8[5], a8[6], a8[7]);
    }
}

extern "C" void kernel_launch(void* const* d_in, const int* in_sizes, int n_in,
                              void* d_out, int out_size, void* d_ws, size_t ws_size,
                              hipStream_t stream) {
    const float* x = (const float*)d_in[0];
    const float* q = (const float*)d_in[1];
    const float* W = (const float*)d_in[2];
    float* out = (float*)d_out;
    short8* Bg = (short8*)d_ws;   // 64 KB packed bf16 B-fragments (head-packed)

    pack_w<<<16, 256, 0, stream>>>(W, Bg);
    fused4<<<(T_DIM / 16) * B_DIM, 512, 0, stream>>>(x, q, Bg, out);
}